// Round 5
// baseline (391.662 us; speedup 1.0000x reference)
//
#include <hip/hip_runtime.h>
#include <hip/hip_bf16.h>
#include <hip/hip_cooperative_groups.h>
#include <math.h>

namespace cg = cooperative_groups;

// B=2, S=1024, D=512, H=8, hd=64.  M = B*S = 2048.
// Chunked causal linear attention, chunk C=128, NC=8, BH=16.
// Single cooperative kernel: prep -> qkvGEMM -> Mc -> attn -> projGEMM -> gateGEMM.

typedef __bf16 bf16x8 __attribute__((ext_vector_type(8)));
typedef __bf16 bf16x4 __attribute__((ext_vector_type(4)));
typedef float f32x4 __attribute__((ext_vector_type(4)));

#define MFMA16(a, b, c) __builtin_amdgcn_mfma_f32_16x16x32_bf16(a, b, c, 0, 0, 0)

__device__ __forceinline__ float elu1(float v) { return v > 0.f ? v + 1.f : __expf(v); }

__device__ __forceinline__ void gload16(const void* g, void* l) {
    __builtin_amdgcn_global_load_lds((const __attribute__((address_space(1))) void*)g,
                                     (__attribute__((address_space(3))) void*)l, 16, 0, 0);
}

struct SmemG {
    __bf16 sA[2 * 128 * 32];
    __bf16 sB[2 * 128 * 32];
};
struct SmemA {
    __bf16 sQ[128 * 72];
    __bf16 sP[128 * 136];
    __bf16 sM[64 * 72];
    float den2[128];
    float dpart[2][128];
    float ksst[64];
};
struct SmemP {
    float t[32][33];
};
union SmemU {
    SmemG g;
    SmemA a;
    SmemP p;
};

// 64x64-tile GEMM stage (2-phase dbuf), MODE 1: proj epilogue, MODE 2: gate epilogue.
template <int MODE>
__device__ __forceinline__ void gemm64(SmemG& g, int tid, int bm, int bn,
                                       const __bf16* __restrict__ A, const __bf16* __restrict__ A2,
                                       const __bf16* __restrict__ Bw, const float* __restrict__ bias,
                                       const float* __restrict__ xf, const float* __restrict__ prj,
                                       float* __restrict__ outf, __bf16* __restrict__ outb, int K) {
    int w = tid >> 6, l = tid & 63;
    int wr = (w >> 1) * 32, wc = (w & 1) * 32;
    int r = tid >> 2, c = (tid & 3) * 8;
    f32x4 acc[2][2] = {};
    const int nt = K / 32;
    auto stage = [&](int t, int buf) {
        int k0 = t * 32;
        const __bf16* a0 = A;
        int gka = k0, lda = K;
        if (MODE == 2) {
            lda = 512;
            if (k0 >= 512) { a0 = A2; gka = k0 - 512; }
        }
        gload16(&a0[(size_t)(bm * 64 + r) * lda + gka + c], &g.sA[buf * 2048 + w * 512]);
        gload16(&Bw[(size_t)(bn * 64 + r) * K + k0 + c], &g.sB[buf * 2048 + w * 512]);
    };
    stage(0, 0);
    __syncthreads();
    int cur = 0;
    for (int t = 0; t < nt; t++) {
        if (t + 1 < nt) stage(t + 1, cur ^ 1);
        bf16x8 af[2], bfr[2];
#pragma unroll
        for (int mi = 0; mi < 2; mi++)
            af[mi] = *(const bf16x8*)&g.sA[cur * 2048 + (wr + mi * 16 + (l & 15)) * 32 + ((l >> 4) << 3)];
#pragma unroll
        for (int ni = 0; ni < 2; ni++)
            bfr[ni] = *(const bf16x8*)&g.sB[cur * 2048 + (wc + ni * 16 + (l & 15)) * 32 + ((l >> 4) << 3)];
#pragma unroll
        for (int mi = 0; mi < 2; mi++)
#pragma unroll
            for (int ni = 0; ni < 2; ni++)
                acc[mi][ni] = MFMA16(af[mi], bfr[ni], acc[mi][ni]);
        __syncthreads();
        cur ^= 1;
    }
#pragma unroll
    for (int mi = 0; mi < 2; mi++)
#pragma unroll
        for (int ni = 0; ni < 2; ni++)
#pragma unroll
            for (int j = 0; j < 4; j++) {
                int gm = bm * 64 + wr + mi * 16 + ((l >> 4) << 2) + j;
                int gn = bn * 64 + wc + ni * 16 + (l & 15);
                float v = acc[mi][ni][j] + bias[gn];
                if (MODE == 1) {
                    outf[(size_t)gm * 512 + gn] = v;
                    outb[(size_t)gm * 512 + gn] = (__bf16)v;
                } else {
                    float gt = 1.f / (1.f + __expf(-v));
                    float xv = xf[(size_t)gm * 512 + gn];
                    float pv = prj[(size_t)gm * 512 + gn];
                    outf[(size_t)gm * 512 + gn] = xv + gt * (pv - xv);
                }
            }
}

__global__ __launch_bounds__(256) void mega_kernel(
    const float* __restrict__ x, const float* __restrict__ Wq, const float* __restrict__ Wk,
    const float* __restrict__ Wv, const float* __restrict__ Wo, const float* __restrict__ bo,
    const float* __restrict__ Wg, const float* __restrict__ bg, float* __restrict__ out,
    __bf16* __restrict__ xb, __bf16* __restrict__ wqkvT, __bf16* __restrict__ woT,
    __bf16* __restrict__ wgT, __bf16* __restrict__ qb, __bf16* __restrict__ kb,
    __bf16* __restrict__ ktb, __bf16* __restrict__ vtb, float* __restrict__ Mc,
    float* __restrict__ ksc, __bf16* __restrict__ attn, float* __restrict__ proj,
    __bf16* __restrict__ projb) {
    cg::grid_group gg = cg::this_grid();
    __shared__ SmemU sm;
    const int bid = blockIdx.x, tid = threadIdx.x;
    const int w = tid >> 6, l = tid & 63;

    // ================= stage 0: prep (x->bf16; 5 weight transposes, 1536 tiles of 32x32)
    {
#pragma unroll
        for (int rep = 0; rep < 2; rep++) {
            int idx = rep * 65536 + bid * 256 + tid;
            int base = idx * 8;
            bf16x8 o;
#pragma unroll
            for (int j = 0; j < 8; j++) o[j] = (__bf16)x[base + j];
            *(bf16x8*)&xb[base] = o;
        }
        for (int t6 = 0; t6 < 6; t6++) {
            int tile = t6 * 256 + bid;
            const float* in;
            __bf16* outp;
            int R, local;
            if (tile < 1024) {
                int m = tile >> 8;
                local = tile & 255;
                R = 512;
                if (m == 0) { in = Wq; outp = wqkvT; }
                else if (m == 1) { in = Wk; outp = wqkvT + (size_t)512 * 512; }
                else if (m == 2) { in = Wv; outp = wqkvT + (size_t)1024 * 512; }
                else { in = Wo; outp = woT; }
            } else {
                local = tile - 1024;
                R = 1024;
                in = Wg;
                outp = wgT;
            }
            int by = local >> 4, bx = local & 15;
            int tx = tid & 31, ty = tid >> 5;
            __syncthreads();
#pragma unroll
            for (int i = 0; i < 32; i += 8)
                sm.p.t[ty + i][tx] = in[(size_t)(by * 32 + ty + i) * 512 + bx * 32 + tx];
            __syncthreads();
#pragma unroll
            for (int i = 0; i < 32; i += 8)
                outp[(size_t)(bx * 32 + ty + i) * R + by * 32 + tx] = (__bf16)sm.p.t[tx][ty + i];
        }
    }
    __threadfence();
    gg.sync();

    // ================= stage 1: qkv GEMM, 192 tiles of 128x128, K=512
    if (bid < 192) {
        int bm = bid & 15, bn = bid >> 4;
        int wr = (w >> 1) * 64, wc = (w & 1) * 64;
        int r = tid >> 2, c = (tid & 3) * 8;
        f32x4 acc[4][4] = {};
        auto stage = [&](int t, int buf) {
            int k0 = t * 32;
#pragma unroll
            for (int i = 0; i < 2; i++)
                gload16(&xb[(size_t)(bm * 128 + i * 64 + r) * 512 + k0 + c],
                        &sm.g.sA[buf * 4096 + i * 2048 + w * 512]);
#pragma unroll
            for (int i = 0; i < 2; i++)
                gload16(&wqkvT[(size_t)(bn * 128 + i * 64 + r) * 512 + k0 + c],
                        &sm.g.sB[buf * 4096 + i * 2048 + w * 512]);
        };
        stage(0, 0);
        __syncthreads();
        int cur = 0;
        for (int t = 0; t < 16; t++) {
            if (t + 1 < 16) stage(t + 1, cur ^ 1);
            bf16x8 af[4], bfr[4];
#pragma unroll
            for (int mi = 0; mi < 4; mi++)
                af[mi] = *(const bf16x8*)&sm.g.sA[cur * 4096 + (wr + mi * 16 + (l & 15)) * 32 + ((l >> 4) << 3)];
#pragma unroll
            for (int ni = 0; ni < 4; ni++)
                bfr[ni] = *(const bf16x8*)&sm.g.sB[cur * 4096 + (wc + ni * 16 + (l & 15)) * 32 + ((l >> 4) << 3)];
#pragma unroll
            for (int mi = 0; mi < 4; mi++)
#pragma unroll
                for (int ni = 0; ni < 4; ni++)
                    acc[mi][ni] = MFMA16(af[mi], bfr[ni], acc[mi][ni]);
            __syncthreads();
            cur ^= 1;
        }
#pragma unroll
        for (int mi = 0; mi < 4; mi++) {
            int gm0 = bm * 128 + wr + mi * 16 + ((l >> 4) << 2);
            int b = gm0 >> 10, s0 = gm0 & 1023;
#pragma unroll
            for (int ni = 0; ni < 4; ni++) {
                int gn = bn * 128 + wc + ni * 16 + (l & 15);
                int which = gn >> 9, h = (gn >> 6) & 7, d = gn & 63;
                int bh = b * 8 + h;
                if (which == 0) {
#pragma unroll
                    for (int j = 0; j < 4; j++)
                        qb[((size_t)(bh * 1024 + s0 + j)) * 64 + d] = (__bf16)elu1(acc[mi][ni][j]);
                } else if (which == 1) {
                    bf16x4 pk;
#pragma unroll
                    for (int j = 0; j < 4; j++) {
                        __bf16 tb = (__bf16)elu1(acc[mi][ni][j]);
                        pk[j] = tb;
                        kb[((size_t)(bh * 1024 + s0 + j)) * 64 + d] = tb;
                    }
                    *(bf16x4*)&ktb[((size_t)(bh * 64 + d)) * 1024 + s0] = pk;
                } else {
                    bf16x4 pv;
#pragma unroll
                    for (int j = 0; j < 4; j++) pv[j] = (__bf16)acc[mi][ni][j];
                    *(bf16x4*)&vtb[((size_t)(bh * 64 + d)) * 1024 + s0] = pv;
                }
            }
        }
    }
    __threadfence();
    gg.sync();

    // ================= stage 2: per-chunk M_c = V^T K + ksum_c (blocks 0..127)
    if (bid < 128) {
        int bh = bid >> 3, ch = bid & 7;
        const __bf16* vb = vtb + (size_t)bh * 65536 + ch * 128;
        const __bf16* kp = ktb + (size_t)bh * 65536 + ch * 128;
        f32x4 macc[4] = {};
#pragma unroll
        for (int ks = 0; ks < 4; ks++) {
            bf16x8 a = *(const bf16x8*)&vb[(size_t)(w * 16 + (l & 15)) * 1024 + ks * 32 + ((l >> 4) << 3)];
#pragma unroll
            for (int ni = 0; ni < 4; ni++) {
                bf16x8 bb = *(const bf16x8*)&kp[(size_t)(ni * 16 + (l & 15)) * 1024 + ks * 32 + ((l >> 4) << 3)];
                macc[ni] = MFMA16(a, bb, macc[ni]);
            }
        }
        float* mout = Mc + (size_t)bid * 4096;
#pragma unroll
        for (int ni = 0; ni < 4; ni++)
#pragma unroll
            for (int j = 0; j < 4; j++)
                mout[(size_t)(w * 16 + ((l >> 4) << 2) + j) * 64 + ni * 16 + (l & 15)] = macc[ni][j];
        if (tid < 64) {
            float s = 0.f;
            const __bf16* kr = ktb + (size_t)(bh * 64 + tid) * 1024 + ch * 128;
#pragma unroll
            for (int t = 0; t < 16; t++) {
                bf16x8 v = *(const bf16x8*)&kr[t * 8];
#pragma unroll
                for (int j = 0; j < 8; j++) s += (float)v[j];
            }
            ksc[bid * 64 + tid] = s;
        }
    }
    __threadfence();
    gg.sync();

    // ================= stage 3: per-chunk causal attention (blocks 0..127)
    if (bid < 128) {
        int bh = bid >> 3, ch = bid & 7;
        int b = bh >> 3, h = bh & 7;

        const __bf16* qsrc = qb + (size_t)(bh * 1024 + ch * 128) * 64;
#pragma unroll
        for (int i = 0; i < 4; i++) {
            int e = i * 2048 + tid * 8;
            *(bf16x8*)&sm.a.sQ[(e >> 6) * 72 + (e & 63)] = *(const bf16x8*)&qsrc[e];
        }
        {
            int r0 = tid >> 2;
            int c0 = (tid & 3) * 16;
            f32x4 s0 = {}, s1 = {}, s2 = {}, s3 = {};
            const float* mcb = Mc + (size_t)(bh * 8) * 4096 + r0 * 64 + c0;
            for (int c = 0; c < ch; c++) {
                const float* p = mcb + (size_t)c * 4096;
                s0 += *(const f32x4*)&p[0];
                s1 += *(const f32x4*)&p[4];
                s2 += *(const f32x4*)&p[8];
                s3 += *(const f32x4*)&p[12];
            }
            __bf16* d = &sm.a.sM[r0 * 72 + c0];
#pragma unroll
            for (int j = 0; j < 4; j++) {
                d[j] = (__bf16)s0[j];
                d[4 + j] = (__bf16)s1[j];
                d[8 + j] = (__bf16)s2[j];
                d[12 + j] = (__bf16)s3[j];
            }
        }
        if (tid < 64) {
            float s = 0.f;
            for (int c = 0; c < ch; c++) s += ksc[(bh * 8 + c) * 64 + tid];
            sm.a.ksst[tid] = s;
        }
        __syncthreads();

        if (w == 1) {
#pragma unroll
            for (int rr = 0; rr < 2; rr++) {
                int row = rr * 64 + l;
                float s = 0.f;
#pragma unroll
                for (int d0 = 0; d0 < 64; d0 += 8) {
                    bf16x8 qv = *(const bf16x8*)&sm.a.sQ[row * 72 + d0];
#pragma unroll
                    for (int jj = 0; jj < 8; jj++) s += (float)qv[jj] * sm.a.ksst[d0 + jj];
                }
                sm.a.den2[row] = s;
            }
            sm.a.dpart[1][l] = 0.f;
        } else {
            int wr = (w == 0) ? 0 : 64;
            int wc = (w == 3) ? 64 : 0;
            const bool diag = (w != 2);
            f32x4 acc[4][4] = {};
            const __bf16* kbase = kb + (size_t)(bh * 1024 + ch * 128) * 64;
#pragma unroll
            for (int ks = 0; ks < 2; ks++) {
                bf16x8 a[4], bfr[4];
#pragma unroll
                for (int mi = 0; mi < 4; mi++)
                    a[mi] = *(const bf16x8*)&sm.a.sQ[(wr + mi * 16 + (l & 15)) * 72 + ks * 32 + ((l >> 4) << 3)];
#pragma unroll
                for (int ni = 0; ni < 4; ni++)
                    bfr[ni] = *(const bf16x8*)&kbase[(size_t)(wc + ni * 16 + (l & 15)) * 64 + ks * 32 + ((l >> 4) << 3)];
#pragma unroll
                for (int mi = 0; mi < 4; mi++)
#pragma unroll
                    for (int ni = 0; ni < 4; ni++)
                        acc[mi][ni] = MFMA16(a[mi], bfr[ni], acc[mi][ni]);
            }
            int dp = (w == 3) ? 1 : 0;
#pragma unroll
            for (int mi = 0; mi < 4; mi++) {
#pragma unroll
                for (int j = 0; j < 4; j++) {
                    int row = wr + mi * 16 + ((l >> 4) << 2) + j;
                    float rs = 0.f;
#pragma unroll
                    for (int ni = 0; ni < 4; ni++) {
                        int col = wc + ni * 16 + (l & 15);
                        float v = acc[mi][ni][j];
                        if (diag) v = (col <= row) ? v : 0.f;
                        rs += v;
                        sm.a.sP[row * 136 + col] = (__bf16)v;
                    }
#pragma unroll
                    for (int off = 1; off < 16; off <<= 1) rs += __shfl_xor(rs, off);
                    if ((l & 15) == 0) sm.a.dpart[dp][row] = rs;
                }
            }
        }
        __syncthreads();

        f32x4 o[2][4] = {};
        const __bf16* vbase = vtb + (size_t)bh * 65536 + ch * 128;
        for (int ks = 0; ks <= w; ks++) {
            bf16x8 a[2], bfr[4];
#pragma unroll
            for (int mi = 0; mi < 2; mi++)
                a[mi] = *(const bf16x8*)&sm.a.sP[(w * 32 + mi * 16 + (l & 15)) * 136 + ks * 32 + ((l >> 4) << 3)];
#pragma unroll
            for (int ni = 0; ni < 4; ni++)
                bfr[ni] = *(const bf16x8*)&vbase[(size_t)(ni * 16 + (l & 15)) * 1024 + ks * 32 + ((l >> 4) << 3)];
#pragma unroll
            for (int mi = 0; mi < 2; mi++)
#pragma unroll
                for (int ni = 0; ni < 4; ni++)
                    o[mi][ni] = MFMA16(a[mi], bfr[ni], o[mi][ni]);
        }
        if (ch > 0) {
#pragma unroll
            for (int ks = 0; ks < 2; ks++) {
                bf16x8 a[2], bfr[4];
#pragma unroll
                for (int mi = 0; mi < 2; mi++)
                    a[mi] = *(const bf16x8*)&sm.a.sQ[(w * 32 + mi * 16 + (l & 15)) * 72 + ks * 32 + ((l >> 4) << 3)];
#pragma unroll
                for (int ni = 0; ni < 4; ni++)
                    bfr[ni] = *(const bf16x8*)&sm.a.sM[(ni * 16 + (l & 15)) * 72 + ks * 32 + ((l >> 4) << 3)];
#pragma unroll
                for (int mi = 0; mi < 2; mi++)
#pragma unroll
                    for (int ni = 0; ni < 4; ni++)
                        o[mi][ni] = MFMA16(a[mi], bfr[ni], o[mi][ni]);
            }
        }

        __bf16* obase = attn + ((size_t)(b * 1024 + ch * 128)) * 512 + h * 64;
#pragma unroll
        for (int mi = 0; mi < 2; mi++)
#pragma unroll
            for (int j = 0; j < 4; j++) {
                int row = w * 32 + mi * 16 + ((l >> 4) << 2) + j;
                float dn = sm.a.den2[row] + sm.a.dpart[0][row] + sm.a.dpart[1][row] + 1e-6f;
#pragma unroll
                for (int ni = 0; ni < 4; ni++) {
                    int col = ni * 16 + (l & 15);
                    obase[(size_t)row * 512 + col] = (__bf16)(o[mi][ni][j] / dn);
                }
            }
    }
    __threadfence();
    gg.sync();

    // ================= stage 4: proj GEMM, 256 tiles of 64x64, K=512
    gemm64<1>(sm.g, tid, bid & 31, bid >> 5, attn, nullptr, woT, bo, nullptr, nullptr, proj, projb, 512);
    __threadfence();
    gg.sync();

    // ================= stage 5: gate GEMM, 256 tiles of 64x64, K=1024
    gemm64<2>(sm.g, tid, bid & 31, bid >> 5, xb, projb, wgT, bg, x, proj, out, nullptr, 1024);
}

// ----------------------------------------------------------------
extern "C" void kernel_launch(void* const* d_in, const int* in_sizes, int n_in,
                              void* d_out, int out_size, void* d_ws, size_t ws_size,
                              hipStream_t stream) {
    const float* x = (const float*)d_in[0];
    const float* Wq = (const float*)d_in[1];
    const float* Wk = (const float*)d_in[2];
    const float* Wv = (const float*)d_in[3];
    const float* Wo = (const float*)d_in[4];
    const float* bo = (const float*)d_in[5];
    const float* Wg = (const float*)d_in[6];
    const float* bg = (const float*)d_in[7];
    float* out = (float*)d_out;

    char* ws = (char*)d_ws;
    size_t off = 0;
    auto alloc = [&](size_t bytes) -> void* {
        void* p = ws + off;
        off += (bytes + 255) & ~(size_t)255;
        return p;
    };
    __bf16* xb    = (__bf16*)alloc((size_t)2048 * 512 * 2);
    __bf16* wqkvT = (__bf16*)alloc((size_t)1536 * 512 * 2);
    __bf16* woT   = (__bf16*)alloc((size_t)512 * 512 * 2);
    __bf16* wgT   = (__bf16*)alloc((size_t)512 * 1024 * 2);
    __bf16* qb    = (__bf16*)alloc((size_t)16 * 1024 * 64 * 2);
    __bf16* kb    = (__bf16*)alloc((size_t)16 * 1024 * 64 * 2);
    __bf16* ktb   = (__bf16*)alloc((size_t)16 * 64 * 1024 * 2);
    __bf16* vtb   = (__bf16*)alloc((size_t)16 * 64 * 1024 * 2);
    float*  Mc    = (float*)alloc((size_t)128 * 4096 * 4);
    float*  ksc   = (float*)alloc((size_t)128 * 64 * 4);
    __bf16* attn  = (__bf16*)alloc((size_t)2048 * 512 * 2);
    float*  proj  = (float*)alloc((size_t)2048 * 512 * 4);
    __bf16* projb = (__bf16*)alloc((size_t)2048 * 512 * 2);

    void* kargs[] = {(void*)&x,  (void*)&Wq,  (void*)&Wk,  (void*)&Wv,   (void*)&Wo,
                     (void*)&bo, (void*)&Wg,  (void*)&bg,  (void*)&out,  (void*)&xb,
                     (void*)&wqkvT, (void*)&woT, (void*)&wgT, (void*)&qb, (void*)&kb,
                     (void*)&ktb, (void*)&vtb, (void*)&Mc,  (void*)&ksc, (void*)&attn,
                     (void*)&proj, (void*)&projb};
    hipLaunchCooperativeKernel((void*)mega_kernel, dim3(256), dim3(256), kargs, 0, stream);
}

// Round 6
// 65.707 us; speedup vs baseline: 5.9607x; 5.9607x over previous
//
#include <hip/hip_runtime.h>
#include <hip/hip_bf16.h>
#include <math.h>

// B=2, S=1024, D=512, H=8, hd=64.  M = B*S = 2048.
// Chunked causal linear attention, chunk C=128, NC=8 chunks, BH = B*H = 16.
// GEMMs: 3-deep global_load_lds pipeline with counted vmcnt (T3/T4-minimal),
// raw s_barrier; loads for tile t+1 stay in flight across barrier(t).

typedef __bf16 bf16x8 __attribute__((ext_vector_type(8)));
typedef __bf16 bf16x4 __attribute__((ext_vector_type(4)));
typedef float f32x4 __attribute__((ext_vector_type(4)));

#define MFMA16(a, b, c) __builtin_amdgcn_mfma_f32_16x16x32_bf16(a, b, c, 0, 0, 0)

__device__ __forceinline__ float elu1(float v) { return v > 0.f ? v + 1.f : __expf(v); }

__device__ __forceinline__ void gload16(const void* g, void* l) {
    __builtin_amdgcn_global_load_lds((const __attribute__((address_space(1))) void*)g,
                                     (__attribute__((address_space(3))) void*)l, 16, 0, 0);
}

// ---------------------------------------------------------------- prep: x->bf16 + 5 weight transposes
__global__ __launch_bounds__(256) void prep_kernel(
    const float* __restrict__ x, const float* __restrict__ Wq, const float* __restrict__ Wk,
    const float* __restrict__ Wv, const float* __restrict__ Wo, const float* __restrict__ Wg,
    __bf16* __restrict__ xb, __bf16* __restrict__ wqkvT, __bf16* __restrict__ woT,
    __bf16* __restrict__ wgT) {
    int z = blockIdx.z;
    if (z == 5) {
        int bid = blockIdx.y * 16 + blockIdx.x;
        int base = (bid * 256 + threadIdx.x) * 8;
        bf16x8 o;
#pragma unroll
        for (int j = 0; j < 8; j++) o[j] = (__bf16)x[base + j];
        *(bf16x8*)&xb[base] = o;
        return;
    }
    const float* in;
    __bf16* out;
    int R = 512, C = 512;
    if (z == 0) { in = Wq; out = wqkvT; }
    else if (z == 1) { in = Wk; out = wqkvT + (size_t)512 * 512; }
    else if (z == 2) { in = Wv; out = wqkvT + (size_t)1024 * 512; }
    else if (z == 3) { in = Wo; out = woT; }
    else { in = Wg; out = wgT; R = 1024; }
    if ((int)blockIdx.y * 32 >= R) return;
    __shared__ float t[32][33];
    int bx = blockIdx.x, by = blockIdx.y;
    int tx = threadIdx.x & 31, ty = threadIdx.x >> 5;
#pragma unroll
    for (int i = 0; i < 32; i += 8)
        t[ty + i][tx] = in[(size_t)(by * 32 + ty + i) * C + bx * 32 + tx];
    __syncthreads();
#pragma unroll
    for (int i = 0; i < 32; i += 8)
        out[(size_t)(bx * 32 + ty + i) * R + by * 32 + tx] = (__bf16)t[tx][ty + i];
}

// ---------------------------------------------------------------- pipelined GEMM (BMxBN tile, BK=32, depth 3)
// A row-major [M][K] bf16 ; Bw row-major [N][K] bf16 (B^T) ; fp32 accum.
// MODE 0: qkv epilogue; MODE 1: proj epilogue; MODE 2: gate epilogue.
template <int MODE, int BM, int BN>
__global__ __launch_bounds__(256) void gemm_kernel(
    const __bf16* __restrict__ A, const __bf16* __restrict__ A2,
    const __bf16* __restrict__ Bw, const float* __restrict__ bias,
    const float* __restrict__ xf, const float* __restrict__ proj,
    float* __restrict__ outf, __bf16* __restrict__ outb,
    __bf16* __restrict__ q_out, __bf16* __restrict__ k_out,
    __bf16* __restrict__ kt_out, __bf16* __restrict__ vt_out, int K) {
    constexpr int MI = BM / 32, NI = BN / 32;
    constexpr int LA = BM / 64, LB = BN / 64;
    constexpr int L = LA + LB;  // gload16 per wave per step
    __shared__ __bf16 sA[3 * BM * 32];
    __shared__ __bf16 sB[3 * BN * 32];
    int bm = blockIdx.x, bn = blockIdx.y;
    int tid = threadIdx.x, w = tid >> 6, l = tid & 63;
    int wr = (w >> 1) * (16 * MI), wc = (w & 1) * (16 * NI);
    int r = tid >> 2, c = (tid & 3) * 8;
    f32x4 acc[MI][NI] = {};
    const int nt = K / 32;

    auto stage = [&](int t, int buf) {
        int k0 = t * 32;
        const __bf16* a0 = A;
        int gka = k0, lda = K;
        if (MODE == 2) {
            lda = 512;
            if (k0 >= 512) { a0 = A2; gka = k0 - 512; }
        }
#pragma unroll
        for (int i = 0; i < LA; i++)
            gload16(&a0[(size_t)(bm * BM + i * 64 + r) * lda + gka + c],
                    &sA[buf * (BM * 32) + i * 2048 + w * 512]);
#pragma unroll
        for (int i = 0; i < LB; i++)
            gload16(&Bw[(size_t)(bn * BN + i * 64 + r) * K + k0 + c],
                    &sB[buf * (BN * 32) + i * 2048 + w * 512]);
    };

    stage(0, 0);
    stage(1, 1);
    for (int t = 0; t < nt; t++) {
        // wait: tile t's loads complete (tile t+1's L loads may stay in flight)
        if (t + 1 < nt) {
            if constexpr (L == 2) asm volatile("s_waitcnt vmcnt(2)" ::: "memory");
            else asm volatile("s_waitcnt vmcnt(3)" ::: "memory");
        } else {
            asm volatile("s_waitcnt vmcnt(0)" ::: "memory");
        }
        asm volatile("s_barrier" ::: "memory");
        // all reads of buf[(t+2)%3] (tile t-1) retired before this barrier -> safe to overwrite
        if (t + 2 < nt) stage(t + 2, (t + 2) % 3);
        int buf = t % 3;
        bf16x8 af[MI], bfr[NI];
#pragma unroll
        for (int mi = 0; mi < MI; mi++)
            af[mi] = *(const bf16x8*)&sA[buf * (BM * 32) + (wr + mi * 16 + (l & 15)) * 32 + ((l >> 4) << 3)];
#pragma unroll
        for (int ni = 0; ni < NI; ni++)
            bfr[ni] = *(const bf16x8*)&sB[buf * (BN * 32) + (wc + ni * 16 + (l & 15)) * 32 + ((l >> 4) << 3)];
#pragma unroll
        for (int mi = 0; mi < MI; mi++)
#pragma unroll
            for (int ni = 0; ni < NI; ni++)
                acc[mi][ni] = MFMA16(af[mi], bfr[ni], acc[mi][ni]);
    }

    if (MODE == 0) {
#pragma unroll
        for (int mi = 0; mi < MI; mi++) {
            int gm0 = bm * BM + wr + mi * 16 + ((l >> 4) << 2);
            int b = gm0 >> 10, s0 = gm0 & 1023;
#pragma unroll
            for (int ni = 0; ni < NI; ni++) {
                int gn = bn * BN + wc + ni * 16 + (l & 15);
                int which = gn >> 9, h = (gn >> 6) & 7, d = gn & 63;
                int bh = b * 8 + h;
                if (which == 0) {
#pragma unroll
                    for (int j = 0; j < 4; j++)
                        q_out[((size_t)(bh * 1024 + s0 + j)) * 64 + d] = (__bf16)elu1(acc[mi][ni][j]);
                } else if (which == 1) {
                    bf16x4 pk;
#pragma unroll
                    for (int j = 0; j < 4; j++) {
                        __bf16 tb = (__bf16)elu1(acc[mi][ni][j]);
                        pk[j] = tb;
                        k_out[((size_t)(bh * 1024 + s0 + j)) * 64 + d] = tb;
                    }
                    *(bf16x4*)&kt_out[((size_t)(bh * 64 + d)) * 1024 + s0] = pk;
                } else {
                    bf16x4 pv;
#pragma unroll
                    for (int j = 0; j < 4; j++) pv[j] = (__bf16)acc[mi][ni][j];
                    *(bf16x4*)&vt_out[((size_t)(bh * 64 + d)) * 1024 + s0] = pv;
                }
            }
        }
    } else {
#pragma unroll
        for (int mi = 0; mi < MI; mi++)
#pragma unroll
            for (int ni = 0; ni < NI; ni++)
#pragma unroll
                for (int j = 0; j < 4; j++) {
                    int gm = bm * BM + wr + mi * 16 + ((l >> 4) << 2) + j;
                    int gn = bn * BN + wc + ni * 16 + (l & 15);
                    float v = acc[mi][ni][j] + bias[gn];
                    if (MODE == 1) {
                        outf[(size_t)gm * 512 + gn] = v;
                        outb[(size_t)gm * 512 + gn] = (__bf16)v;
                    } else {
                        float g = 1.f / (1.f + __expf(-v));
                        float xv = xf[(size_t)gm * 512 + gn];
                        float pv = proj[(size_t)gm * 512 + gn];
                        outf[(size_t)gm * 512 + gn] = xv + g * (pv - xv);
                    }
                }
    }
}

// ---------------------------------------------------------------- per-chunk M_c = V^T K + ksum_c
__global__ __launch_bounds__(256) void mc_kernel(const __bf16* __restrict__ ktb,
                                                 const __bf16* __restrict__ vtb,
                                                 float* __restrict__ Mc, float* __restrict__ ksc) {
    int blk = blockIdx.x;
    int bh = blk >> 3, ch = blk & 7;
    int tid = threadIdx.x, w = tid >> 6, l = tid & 63;
    const __bf16* vb = vtb + (size_t)bh * 65536 + ch * 128;
    const __bf16* kp = ktb + (size_t)bh * 65536 + ch * 128;
    f32x4 macc[4] = {};
#pragma unroll
    for (int ks = 0; ks < 4; ks++) {
        bf16x8 a = *(const bf16x8*)&vb[(size_t)(w * 16 + (l & 15)) * 1024 + ks * 32 + ((l >> 4) << 3)];
#pragma unroll
        for (int ni = 0; ni < 4; ni++) {
            bf16x8 bb = *(const bf16x8*)&kp[(size_t)(ni * 16 + (l & 15)) * 1024 + ks * 32 + ((l >> 4) << 3)];
            macc[ni] = MFMA16(a, bb, macc[ni]);
        }
    }
    float* mout = Mc + (size_t)blk * 4096;
#pragma unroll
    for (int ni = 0; ni < 4; ni++)
#pragma unroll
        for (int j = 0; j < 4; j++)
            mout[(size_t)(w * 16 + ((l >> 4) << 2) + j) * 64 + ni * 16 + (l & 15)] = macc[ni][j];
    if (tid < 64) {
        float s = 0.f;
        const __bf16* kr = ktb + (size_t)(bh * 64 + tid) * 1024 + ch * 128;
#pragma unroll
        for (int t = 0; t < 16; t++) {
            bf16x8 v = *(const bf16x8*)&kr[t * 8];
#pragma unroll
            for (int j = 0; j < 8; j++) s += (float)v[j];
        }
        ksc[blk * 64 + tid] = s;
    }
}

// ---------------------------------------------------------------- per-chunk causal attention
__global__ __launch_bounds__(256) void attn_chunk_kernel(
    const __bf16* __restrict__ qb, const __bf16* __restrict__ kb,
    const __bf16* __restrict__ vtb, const float* __restrict__ Mc,
    const float* __restrict__ ksc, __bf16* __restrict__ attn_out) {
    int blk = blockIdx.x;
    int bh = blk >> 3, ch = blk & 7;
    int b = bh >> 3, h = bh & 7;
    int tid = threadIdx.x, w = tid >> 6, l = tid & 63;

    __shared__ __bf16 sQ[128 * 72];
    __shared__ __bf16 sP[128 * 136];
    __shared__ __bf16 sM[64 * 72];
    __shared__ float den2[128];
    __shared__ float dpart[2][128];
    __shared__ float ksst[64];

    const __bf16* qsrc = qb + (size_t)(bh * 1024 + ch * 128) * 64;
#pragma unroll
    for (int i = 0; i < 4; i++) {
        int e = i * 2048 + tid * 8;
        *(bf16x8*)&sQ[(e >> 6) * 72 + (e & 63)] = *(const bf16x8*)&qsrc[e];
    }
    {
        int r0 = tid >> 2;
        int c0 = (tid & 3) * 16;
        f32x4 s0 = {}, s1 = {}, s2 = {}, s3 = {};
        const float* mcb = Mc + (size_t)(bh * 8) * 4096 + r0 * 64 + c0;
        for (int c = 0; c < ch; c++) {
            const float* p = mcb + (size_t)c * 4096;
            s0 += *(const f32x4*)&p[0];
            s1 += *(const f32x4*)&p[4];
            s2 += *(const f32x4*)&p[8];
            s3 += *(const f32x4*)&p[12];
        }
        __bf16* d = &sM[r0 * 72 + c0];
#pragma unroll
        for (int j = 0; j < 4; j++) {
            d[j] = (__bf16)s0[j];
            d[4 + j] = (__bf16)s1[j];
            d[8 + j] = (__bf16)s2[j];
            d[12 + j] = (__bf16)s3[j];
        }
    }
    if (tid < 64) {
        float s = 0.f;
        for (int c = 0; c < ch; c++) s += ksc[(bh * 8 + c) * 64 + tid];
        ksst[tid] = s;
    }
    __syncthreads();

    if (w == 1) {
#pragma unroll
        for (int rr = 0; rr < 2; rr++) {
            int row = rr * 64 + l;
            float s = 0.f;
#pragma unroll
            for (int d0 = 0; d0 < 64; d0 += 8) {
                bf16x8 qv = *(const bf16x8*)&sQ[row * 72 + d0];
#pragma unroll
                for (int jj = 0; jj < 8; jj++) s += (float)qv[jj] * ksst[d0 + jj];
            }
            den2[row] = s;
        }
        dpart[1][l] = 0.f;
    } else {
        int wr = (w == 0) ? 0 : 64;
        int wc = (w == 3) ? 64 : 0;
        const bool diag = (w != 2);
        f32x4 acc[4][4] = {};
        const __bf16* kbase = kb + (size_t)(bh * 1024 + ch * 128) * 64;
#pragma unroll
        for (int ks = 0; ks < 2; ks++) {
            bf16x8 a[4], bfr[4];
#pragma unroll
            for (int mi = 0; mi < 4; mi++)
                a[mi] = *(const bf16x8*)&sQ[(wr + mi * 16 + (l & 15)) * 72 + ks * 32 + ((l >> 4) << 3)];
#pragma unroll
            for (int ni = 0; ni < 4; ni++)
                bfr[ni] = *(const bf16x8*)&kbase[(size_t)(wc + ni * 16 + (l & 15)) * 64 + ks * 32 + ((l >> 4) << 3)];
#pragma unroll
            for (int mi = 0; mi < 4; mi++)
#pragma unroll
                for (int ni = 0; ni < 4; ni++)
                    acc[mi][ni] = MFMA16(a[mi], bfr[ni], acc[mi][ni]);
        }
        int dp = (w == 3) ? 1 : 0;
#pragma unroll
        for (int mi = 0; mi < 4; mi++) {
#pragma unroll
            for (int j = 0; j < 4; j++) {
                int row = wr + mi * 16 + ((l >> 4) << 2) + j;
                float rs = 0.f;
#pragma unroll
                for (int ni = 0; ni < 4; ni++) {
                    int col = wc + ni * 16 + (l & 15);
                    float v = acc[mi][ni][j];
                    if (diag) v = (col <= row) ? v : 0.f;
                    rs += v;
                    sP[row * 136 + col] = (__bf16)v;
                }
#pragma unroll
                for (int off = 1; off < 16; off <<= 1) rs += __shfl_xor(rs, off);
                if ((l & 15) == 0) dpart[dp][row] = rs;
            }
        }
    }
    __syncthreads();

    f32x4 o[2][4] = {};
    const __bf16* vbase = vtb + (size_t)bh * 65536 + ch * 128;
    for (int ks = 0; ks <= w; ks++) {
        bf16x8 a[2], bfr[4];
#pragma unroll
        for (int mi = 0; mi < 2; mi++)
            a[mi] = *(const bf16x8*)&sP[(w * 32 + mi * 16 + (l & 15)) * 136 + ks * 32 + ((l >> 4) << 3)];
#pragma unroll
        for (int ni = 0; ni < 4; ni++)
            bfr[ni] = *(const bf16x8*)&vbase[(size_t)(ni * 16 + (l & 15)) * 1024 + ks * 32 + ((l >> 4) << 3)];
#pragma unroll
        for (int mi = 0; mi < 2; mi++)
#pragma unroll
            for (int ni = 0; ni < 4; ni++)
                o[mi][ni] = MFMA16(a[mi], bfr[ni], o[mi][ni]);
    }
    if (ch > 0) {
#pragma unroll
        for (int ks = 0; ks < 2; ks++) {
            bf16x8 a[2], bfr[4];
#pragma unroll
            for (int mi = 0; mi < 2; mi++)
                a[mi] = *(const bf16x8*)&sQ[(w * 32 + mi * 16 + (l & 15)) * 72 + ks * 32 + ((l >> 4) << 3)];
#pragma unroll
            for (int ni = 0; ni < 4; ni++)
                bfr[ni] = *(const bf16x8*)&sM[(ni * 16 + (l & 15)) * 72 + ks * 32 + ((l >> 4) << 3)];
#pragma unroll
            for (int mi = 0; mi < 2; mi++)
#pragma unroll
                for (int ni = 0; ni < 4; ni++)
                    o[mi][ni] = MFMA16(a[mi], bfr[ni], o[mi][ni]);
        }
    }

    __bf16* obase = attn_out + ((size_t)(b * 1024 + ch * 128)) * 512 + h * 64;
#pragma unroll
    for (int mi = 0; mi < 2; mi++)
#pragma unroll
        for (int j = 0; j < 4; j++) {
            int row = w * 32 + mi * 16 + ((l >> 4) << 2) + j;
            float dn = den2[row] + dpart[0][row] + dpart[1][row] + 1e-6f;
#pragma unroll
            for (int ni = 0; ni < 4; ni++) {
                int col = ni * 16 + (l & 15);
                obase[(size_t)row * 512 + col] = (__bf16)(o[mi][ni][j] / dn);
            }
        }
}

// ----------------------------------------------------------------
extern "C" void kernel_launch(void* const* d_in, const int* in_sizes, int n_in,
                              void* d_out, int out_size, void* d_ws, size_t ws_size,
                              hipStream_t stream) {
    const float* x = (const float*)d_in[0];
    const float* Wq = (const float*)d_in[1];
    const float* Wk = (const float*)d_in[2];
    const float* Wv = (const float*)d_in[3];
    const float* Wo = (const float*)d_in[4];
    const float* bo = (const float*)d_in[5];
    const float* Wg = (const float*)d_in[6];
    const float* bg = (const float*)d_in[7];
    float* out = (float*)d_out;

    char* ws = (char*)d_ws;
    size_t off = 0;
    auto alloc = [&](size_t bytes) -> void* {
        void* p = ws + off;
        off += (bytes + 255) & ~(size_t)255;
        return p;
    };
    __bf16* xb    = (__bf16*)alloc((size_t)2048 * 512 * 2);
    __bf16* wqkvT = (__bf16*)alloc((size_t)1536 * 512 * 2);
    __bf16* woT   = (__bf16*)alloc((size_t)512 * 512 * 2);
    __bf16* wgT   = (__bf16*)alloc((size_t)512 * 1024 * 2);
    __bf16* qb    = (__bf16*)alloc((size_t)16 * 1024 * 64 * 2);
    __bf16* kb    = (__bf16*)alloc((size_t)16 * 1024 * 64 * 2);
    __bf16* ktb   = (__bf16*)alloc((size_t)16 * 64 * 1024 * 2);
    __bf16* vtb   = (__bf16*)alloc((size_t)16 * 64 * 1024 * 2);
    float*  Mc    = (float*)alloc((size_t)128 * 4096 * 4);
    float*  ksc   = (float*)alloc((size_t)128 * 64 * 4);
    __bf16* attn  = (__bf16*)alloc((size_t)2048 * 512 * 2);
    float*  proj  = (float*)alloc((size_t)2048 * 512 * 4);
    __bf16* projb = (__bf16*)alloc((size_t)2048 * 512 * 2);

    prep_kernel<<<dim3(16, 32, 6), 256, 0, stream>>>(x, Wq, Wk, Wv, Wo, Wg, xb, wqkvT, woT, wgT);
    gemm_kernel<0, 64, 128><<<dim3(32, 12), 256, 0, stream>>>(
        xb, nullptr, wqkvT, nullptr, nullptr, nullptr, nullptr, nullptr, qb, kb, ktb, vtb, 512);
    mc_kernel<<<128, 256, 0, stream>>>(ktb, vtb, Mc, ksc);
    attn_chunk_kernel<<<128, 256, 0, stream>>>(qb, kb, vtb, Mc, ksc, attn);
    gemm_kernel<1, 64, 64><<<dim3(32, 8), 256, 0, stream>>>(
        attn, nullptr, woT, bo, nullptr, nullptr, proj, projb, nullptr, nullptr, nullptr, nullptr, 512);
    gemm_kernel<2, 64, 64><<<dim3(32, 8), 256, 0, stream>>>(
        xb, projb, wgT, bg, x, proj, out, nullptr, nullptr, nullptr, nullptr, nullptr, 1024);
}